// Round 7
// baseline (448.934 us; speedup 1.0000x reference)
//
#include <hip/hip_runtime.h>

#define DD 256
#define TOTROWS (524288 * 2)
#define NBLOCKS 256
#define RPI 32                               // rows per region per block
#define ITERS (TOTROWS / (NBLOCKS * RPI))    // 128
#define XROW 528                             // bf16 row stride bytes (16B pad)
#define XBUF(i) ((i) * (RPI * XROW))         // 4 x tiles (bf16)
#define YBUF(i) (4 * RPI * XROW + (i) * (RPI * XROW))  // 2 y tiles (bf16)
#define LDS_TOTAL (6 * RPI * XROW)           // 101376 -> 1 block/CU

typedef __attribute__((ext_vector_type(8))) short short8;
typedef __attribute__((ext_vector_type(4))) float f32x4;
typedef __attribute__((ext_vector_type(4))) unsigned short u16x4;

__device__ inline unsigned short f2bf(float x) {
    unsigned u = __builtin_bit_cast(unsigned, x);
    u += 0x7fffu + ((u >> 16) & 1u);  // RNE
    return (unsigned short)(u >> 16);
}
__device__ inline float bf2f(unsigned short h) {
    unsigned u = ((unsigned)h) << 16;
    return __builtin_bit_cast(float, u);
}

// LDS-only barrier: orders ds ops across waves WITHOUT draining in-flight
// global loads/stores (vmcnt untouched). All cross-wave hazards are LDS.
__device__ inline void block_sync_lds() {
    __builtin_amdgcn_sched_barrier(0);
    asm volatile("s_waitcnt lgkmcnt(0)" ::: "memory");
    __builtin_amdgcn_s_barrier();
    __builtin_amdgcn_sched_barrier(0);
}

// ---------------- W = Wo @ Wv (bf16), c = Wo @ bv + bo ----------------
__global__ void wprep_kernel(const float* __restrict__ in_w,
                             const float* __restrict__ in_b,
                             const float* __restrict__ out_w,
                             const float* __restrict__ out_b,
                             unsigned short* __restrict__ Wbf,
                             float* __restrict__ cvec) {
    __shared__ float worow[DD];
    __shared__ float part[DD];
    const int i = blockIdx.x;
    const int j = threadIdx.x;
    worow[j] = out_w[i * DD + j];
    __syncthreads();
    const float* wv = in_w + 512 * DD;  // Wv = rows 512..767 of in_proj_w
    float s = 0.f;
    for (int k = 0; k < DD; ++k) s = fmaf(worow[k], wv[k * DD + j], s);
    Wbf[i * DD + j] = f2bf(s);
    part[j] = worow[j] * in_b[512 + j];  // bv[j]
    __syncthreads();
    if (j == 0) {
        float c = out_b[i];
        for (int k = 0; k < DD; ++k) c += part[k];
        cvec[i] = c;
    }
}

// ---------------- main fused kernel ----------------
// 256 blocks x 512 threads, 1 block/CU. W in regs (32 out-cols/wave).
// The 4 per-region phases {LN+store, MFMA+ybuf, stage, load} are mutually
// independent (all hazards cross-region, enforced by the barrier), so
// wave-group k (= wave>>1) executes them rotated by k: global loads and
// stores are issued at 4 staggered points per region -> continuous HBM
// pressure instead of block-wide phase-locked bursts.
__global__ __launch_bounds__(512, 2) void fused_kernel(
    const float* __restrict__ x, const unsigned short* __restrict__ Wbf,
    const float* __restrict__ cvec, const float* __restrict__ gamma,
    const float* __restrict__ beta, float* __restrict__ out) {
    extern __shared__ __align__(16) char lds[];
    const int tid = threadIdx.x;
    const int w = tid >> 6, lane = tid & 63;
    const int grp = tid >> 7;                 // 4 groups x 2 waves
    const int m = lane & 15, g = lane >> 4;
    const int lc = lane & 15, lr = tid >> 4;  // LN: 16 lanes/row, rows 0..31

    short8 af[2][8];
#pragma unroll
    for (int n2 = 0; n2 < 2; ++n2)
#pragma unroll
        for (int s = 0; s < 8; ++s)
            af[n2][s] = *(const short8*)(Wbf + (w * 32 + n2 * 16 + m) * 256 + s * 32 + g * 8);

    f32x4 creg[2];
#pragma unroll
    for (int n2 = 0; n2 < 2; ++n2)
        creg[n2] = *(const f32x4*)(cvec + w * 32 + n2 * 16 + g * 4);
    f32x4 gg[4], bb[4];
#pragma unroll
    for (int k = 0; k < 4; ++k) {
        gg[k] = *(const f32x4*)(gamma + lc * 4 + k * 64);
        bb[k] = *(const f32x4*)(beta + lc * 4 + k * 64);
    }

    const size_t rowbase = (size_t)blockIdx.x * (ITERS * RPI);

    f32x4 svA[4], svB[4];
    // prologue: stage tiles 0,1; leave tile 2 loaded in svA
#pragma unroll
    for (int j = 0; j < 4; ++j)
        svA[j] = *(const f32x4*)(x + rowbase * DD + j * 2048 + tid * 4);
#pragma unroll
    for (int j = 0; j < 4; ++j) {
        const int row = j * 8 + w;
        u16x4 h = {f2bf(svA[j][0]), f2bf(svA[j][1]), f2bf(svA[j][2]), f2bf(svA[j][3])};
        *(u16x4*)(lds + XBUF(0) + row * XROW + lane * 8) = h;
    }
#pragma unroll
    for (int j = 0; j < 4; ++j)
        svA[j] = *(const f32x4*)(x + (rowbase + RPI) * DD + j * 2048 + tid * 4);
#pragma unroll
    for (int j = 0; j < 4; ++j) {
        const int row = j * 8 + w;
        u16x4 h = {f2bf(svA[j][0]), f2bf(svA[j][1]), f2bf(svA[j][2]), f2bf(svA[j][3])};
        *(u16x4*)(lds + XBUF(1) + row * XROW + lane * 8) = h;
    }
#pragma unroll
    for (int j = 0; j < 4; ++j)
        svA[j] = *(const f32x4*)(x + (rowbase + 2 * RPI) * DD + j * 2048 + tid * 4);
    block_sync_lds();

#define P_LN                                                                     \
    if (it > 0) {                                                                \
        const size_t rp = r0 - RPI + lr;                                         \
        u16x4 yh[4];                                                             \
        _Pragma("unroll")                                                        \
        for (int k = 0; k < 4; ++k)                                              \
            yh[k] = *(const u16x4*)(lds + ybB + lr * XROW + lc * 8 + k * 128);   \
        float s1 = 0.f, s2 = 0.f;                                                \
        float fv[4][4];                                                          \
        _Pragma("unroll")                                                        \
        for (int k = 0; k < 4; ++k)                                              \
            _Pragma("unroll")                                                    \
            for (int e = 0; e < 4; ++e) {                                        \
                float v = bf2f(yh[k][e]);                                        \
                fv[k][e] = v;                                                    \
                s1 += v;                                                         \
                s2 = fmaf(v, v, s2);                                             \
            }                                                                    \
        s1 += __shfl_xor(s1, 1); s2 += __shfl_xor(s2, 1);                        \
        s1 += __shfl_xor(s1, 2); s2 += __shfl_xor(s2, 2);                        \
        s1 += __shfl_xor(s1, 4); s2 += __shfl_xor(s2, 4);                        \
        s1 += __shfl_xor(s1, 8); s2 += __shfl_xor(s2, 8);                        \
        const float mu = s1 * (1.f / 256.f);                                     \
        const float var = s2 * (1.f / 256.f) - mu * mu;                          \
        const float rs = rsqrtf(var + 1e-5f);                                    \
        _Pragma("unroll")                                                        \
        for (int k = 0; k < 4; ++k) {                                            \
            f32x4 o;                                                             \
            _Pragma("unroll")                                                    \
            for (int e = 0; e < 4; ++e)                                          \
                o[e] = fmaf((fv[k][e] - mu) * rs, gg[k][e], bb[k][e]);           \
            __builtin_nontemporal_store(o, (f32x4*)(out + rp * DD + lc * 4 + k * 64)); \
        }                                                                        \
    }

#define P_MFMA                                                                   \
    {                                                                            \
        f32x4 acc[2][2];                                                         \
        acc[0][0] = f32x4{0.f, 0.f, 0.f, 0.f};                                   \
        acc[0][1] = f32x4{0.f, 0.f, 0.f, 0.f};                                   \
        acc[1][0] = f32x4{0.f, 0.f, 0.f, 0.f};                                   \
        acc[1][1] = f32x4{0.f, 0.f, 0.f, 0.f};                                   \
        _Pragma("unroll")                                                        \
        for (int t = 0; t < 2; ++t) {                                            \
            const int rowp = t * 16 + (m ^ 1);                                   \
            const char* bbase = lds + xbc + rowp * XROW + g * 16;                \
            _Pragma("unroll")                                                    \
            for (int s = 0; s < 8; ++s) {                                        \
                short8 bf_ = *(const short8*)(bbase + s * 64);                   \
                acc[t][0] = __builtin_amdgcn_mfma_f32_16x16x32_bf16(af[0][s], bf_, acc[t][0], 0, 0, 0); \
                acc[t][1] = __builtin_amdgcn_mfma_f32_16x16x32_bf16(af[1][s], bf_, acc[t][1], 0, 0, 0); \
            }                                                                    \
        }                                                                        \
        _Pragma("unroll")                                                        \
        for (int t = 0; t < 2; ++t) {                                            \
            const int rowm = t * 16 + m;                                         \
            _Pragma("unroll")                                                    \
            for (int n2 = 0; n2 < 2; ++n2) {                                     \
                u16x4 rh = *(const u16x4*)(lds + xbc + rowm * XROW + w * 64 + n2 * 32 + g * 8); \
                f32x4 y = acc[t][n2];                                            \
                _Pragma("unroll")                                                \
                for (int i = 0; i < 4; ++i) y[i] += bf2f(rh[i]) + creg[n2][i];   \
                u16x4 hy = {f2bf(y[0]), f2bf(y[1]), f2bf(y[2]), f2bf(y[3])};     \
                *(u16x4*)(lds + ybA + rowm * XROW + w * 64 + n2 * 32 + g * 8) = hy; \
            }                                                                    \
        }                                                                        \
    }

#define P_STAGE(SVC)                                                             \
    if (it + 2 < ITERS) {                                                        \
        _Pragma("unroll")                                                        \
        for (int j = 0; j < 4; ++j) {                                            \
            const int row = j * 8 + w;                                           \
            u16x4 h = {f2bf(SVC[j][0]), f2bf(SVC[j][1]), f2bf(SVC[j][2]), f2bf(SVC[j][3])}; \
            *(u16x4*)(lds + xbs + row * XROW + lane * 8) = h;                    \
        }                                                                        \
    }

#define P_LOAD(SVN)                                                              \
    if (it + 3 < ITERS) {                                                        \
        _Pragma("unroll")                                                        \
        for (int j = 0; j < 4; ++j)                                              \
            SVN[j] = *(const f32x4*)(x + (r0 + 3 * RPI) * DD + j * 2048 + tid * 4); \
    }

#define REGION(IT, SVC, SVN)                                                     \
    {                                                                            \
        const int it = (IT);                                                     \
        const int xbc = XBUF(it & 3);                                            \
        const int xbs = XBUF((it + 2) & 3);                                      \
        const int ybA = YBUF(it & 1);                                            \
        const int ybB = YBUF((it + 1) & 1);                                      \
        const size_t r0 = rowbase + (size_t)it * RPI;                            \
        switch (grp) {                                                           \
            case 0: { P_LN } P_MFMA P_STAGE(SVC) P_LOAD(SVN) break;              \
            case 1: P_MFMA P_STAGE(SVC) P_LOAD(SVN) { P_LN } break;              \
            case 2: P_STAGE(SVC) P_LOAD(SVN) { P_LN } P_MFMA break;              \
            default: P_LOAD(SVN) { P_LN } P_MFMA P_STAGE(SVC) break;             \
        }                                                                        \
        block_sync_lds();                                                        \
    }

    for (int itb = 0; itb < ITERS; itb += 2) {
        REGION(itb, svA, svB);
        REGION(itb + 1, svB, svA);
    }
#undef REGION
#undef P_LN
#undef P_MFMA
#undef P_STAGE
#undef P_LOAD

    // epilogue: LN + store for last region (ybuf[(ITERS-1)&1])
    {
        const int ybB = YBUF((ITERS - 1) & 1);
        const size_t rp = rowbase + (size_t)(ITERS - 1) * RPI + lr;
        u16x4 yh[4];
#pragma unroll
        for (int k = 0; k < 4; ++k)
            yh[k] = *(const u16x4*)(lds + ybB + lr * XROW + lc * 8 + k * 128);
        float s1 = 0.f, s2 = 0.f;
        float fv[4][4];
#pragma unroll
        for (int k = 0; k < 4; ++k)
#pragma unroll
            for (int e = 0; e < 4; ++e) {
                float v = bf2f(yh[k][e]);
                fv[k][e] = v;
                s1 += v;
                s2 = fmaf(v, v, s2);
            }
        s1 += __shfl_xor(s1, 1); s2 += __shfl_xor(s2, 1);
        s1 += __shfl_xor(s1, 2); s2 += __shfl_xor(s2, 2);
        s1 += __shfl_xor(s1, 4); s2 += __shfl_xor(s2, 4);
        s1 += __shfl_xor(s1, 8); s2 += __shfl_xor(s2, 8);
        const float mu = s1 * (1.f / 256.f);
        const float var = s2 * (1.f / 256.f) - mu * mu;
        const float rs = rsqrtf(var + 1e-5f);
#pragma unroll
        for (int k = 0; k < 4; ++k) {
            f32x4 o;
#pragma unroll
            for (int e = 0; e < 4; ++e)
                o[e] = fmaf((fv[k][e] - mu) * rs, gg[k][e], bb[k][e]);
            __builtin_nontemporal_store(o, (f32x4*)(out + rp * DD + lc * 4 + k * 64));
        }
    }
}

extern "C" void kernel_launch(void* const* d_in, const int* in_sizes, int n_in,
                              void* d_out, int out_size, void* d_ws, size_t ws_size,
                              hipStream_t stream) {
    const float* x     = (const float*)d_in[0];
    const float* in_w  = (const float*)d_in[1];
    const float* in_b  = (const float*)d_in[2];
    const float* out_w = (const float*)d_in[3];
    const float* out_b = (const float*)d_in[4];
    const float* gamma = (const float*)d_in[5];
    const float* beta  = (const float*)d_in[6];
    float* out = (float*)d_out;

    unsigned short* Wbf = (unsigned short*)d_ws;   // 128 KiB bf16 W = Wo@Wv
    float* cvec = (float*)((char*)d_ws + 131072);  // 1 KiB c = Wo@bv + bo

    hipLaunchKernelGGL(wprep_kernel, dim3(256), dim3(256), 0, stream,
                       in_w, in_b, out_w, out_b, Wbf, cvec);

    hipFuncSetAttribute(reinterpret_cast<const void*>(fused_kernel),
                        hipFuncAttributeMaxDynamicSharedMemorySize, LDS_TOTAL);
    hipLaunchKernelGGL(fused_kernel, dim3(NBLOCKS), dim3(512), LDS_TOTAL, stream,
                       x, Wbf, cvec, gamma, beta, out);
}